// Round 14
// baseline (479.890 us; speedup 1.0000x reference)
//
#include <hip/hip_runtime.h>
#include <math.h>

// ManifoldHyperConnectionFuse on MI355X — R13: full-chip co-residency.
// R12 post-mortem: VGPR=52, bank conflicts dead, but Occupancy 38% /
// VALUBusy 31% / HBM 26% -> latency-bound with only 16 waves/CU resident
// (launch_bounds min-waves=4 cap). At VGPR<=64 this kernel qualifies for
// 8 blocks/CU = 32 waves/CU = 100% occupancy, and grid 2048x4 waves
// EXACTLY fills the chip's 8192 wave slots -> whole grid co-resident,
// TLP hides all load latency. R13 = R12 with __launch_bounds__(256, 8).
// Everything else byte-identical (clean A/B on the occupancy theory).

#define NTOK 16

__device__ __forceinline__ unsigned short f2bf(float f) {
    unsigned int u = __float_as_uint(f);
    return (unsigned short)((u + 0x7FFFu + ((u >> 16) & 1u)) >> 16);
}
__device__ __forceinline__ float bflo(unsigned int u) {
    return __uint_as_float(u << 16);
}
__device__ __forceinline__ float bfhi(unsigned int u) {
    return __uint_as_float(u & 0xffff0000u);
}
__device__ __forceinline__ float sigmoid_f(float z) {
    return 1.0f / (1.0f + __expf(-z));
}

// sum over each aligned 16-lane row via DPP row_ror (VALU-only)
__device__ __forceinline__ float row16_sum(float x) {
    x += __int_as_float(__builtin_amdgcn_update_dpp(
        0, __float_as_int(x), 0x121, 0xf, 0xf, false)); // row_ror:1
    x += __int_as_float(__builtin_amdgcn_update_dpp(
        0, __float_as_int(x), 0x122, 0xf, 0xf, false)); // row_ror:2
    x += __int_as_float(__builtin_amdgcn_update_dpp(
        0, __float_as_int(x), 0x124, 0xf, 0xf, false)); // row_ror:4
    x += __int_as_float(__builtin_amdgcn_update_dpp(
        0, __float_as_int(x), 0x128, 0xf, 0xf, false)); // row_ror:8
    return x;
}

// ---- prep: fold alpha*nw*w -> bf16 wt[24][1024] (n-major) in d_ws ----
__global__ __launch_bounds__(256)
void prep_kernel(const float* __restrict__ nw,
                 const float* __restrict__ w,
                 const float* __restrict__ alpha,
                 unsigned short* __restrict__ wt)
{
    const int tid = blockIdx.x * 256 + threadIdx.x;   // 6144 threads
    const int flat = 4 * tid;                          // w is [k][n], flat=k*24+n
    const float4 w4 = *(const float4*)(w + flat);
    const float a0 = alpha[0], a1 = alpha[1], a2 = alpha[2];
    const float vals[4] = {w4.x, w4.y, w4.z, w4.w};
    #pragma unroll
    for (int c = 0; c < 4; ++c) {
        const int f = flat + c;
        const int k = f / 24;
        const int n = f - 24 * k;
        const float as = (n < 4) ? a0 : ((n < 8) ? a1 : a2);
        wt[n * 1024 + k] = f2bf(as * nw[k] * vals[c]);
    }
}

__global__ __launch_bounds__(256, 8)
void mhc_kernel(const float* __restrict__ h,
                const unsigned short* __restrict__ wt,
                const float* __restrict__ beta,
                float* __restrict__ out)
{
    const int tid  = threadIdx.x;
    const int lane = tid & 63;
    const int wv   = tid >> 6;     // wave id: owns tokens [4wv, 4wv+4)
    const int ksl  = lane & 15;    // k-slice lane
    const int ng   = lane >> 4;    // n-group (6 n's each)

    __shared__ float Hpart[NTOK][28];   // [0:24) H, [24] r2
    __shared__ float smalls[NTOK][26];  // Hpre, Hpost, P

    const long tok0 = (long)blockIdx.x * NTOK;
    const int t0 = 4 * wv;
    const float* ph = h + (tok0 + t0) * 1024 + 4 * ksl;
    const unsigned short* pw = wt + (6 * ng) * 1024 + 4 * ksl;

    // ---- phase A: acc-resident, x & w double-buffered across e ----
    float acc[4][6], r2[4];
    #pragma unroll
    for (int t = 0; t < 4; ++t) {
        r2[t] = 0.f;
        #pragma unroll
        for (int j = 0; j < 6; ++j) acc[t][j] = 0.f;
    }

    float4 xa0, xa1, xa2, xa3;
    uint2  wa[6];
    xa0 = *(const float4*)(ph);
    xa1 = *(const float4*)(ph + 1024);
    xa2 = *(const float4*)(ph + 2048);
    xa3 = *(const float4*)(ph + 3072);
    #pragma unroll
    for (int j = 0; j < 6; ++j)
        wa[j] = *(const uint2*)(pw + j * 1024);

    #pragma unroll 1
    for (int e = 0; e < 16; ++e) {
        float4 xb0, xb1, xb2, xb3;
        uint2  wb[6];
        if (e + 1 < 16) {                 // issue e+1 loads before e compute
            const float* p = ph + (e + 1) * 64;
            xb0 = *(const float4*)(p);
            xb1 = *(const float4*)(p + 1024);
            xb2 = *(const float4*)(p + 2048);
            xb3 = *(const float4*)(p + 3072);
            const unsigned short* q = pw + (e + 1) * 64;
            #pragma unroll
            for (int j = 0; j < 6; ++j)
                wb[j] = *(const uint2*)(q + j * 1024);
        }

        #pragma unroll
        for (int j = 0; j < 6; ++j) {
            const float w0 = bflo(wa[j].x), w1 = bfhi(wa[j].x);
            const float w2 = bflo(wa[j].y), w3 = bfhi(wa[j].y);
            acc[0][j] = fmaf(xa0.w, w3, fmaf(xa0.z, w2,
                        fmaf(xa0.y, w1, fmaf(xa0.x, w0, acc[0][j]))));
            acc[1][j] = fmaf(xa1.w, w3, fmaf(xa1.z, w2,
                        fmaf(xa1.y, w1, fmaf(xa1.x, w0, acc[1][j]))));
            acc[2][j] = fmaf(xa2.w, w3, fmaf(xa2.z, w2,
                        fmaf(xa2.y, w1, fmaf(xa2.x, w0, acc[2][j]))));
            acc[3][j] = fmaf(xa3.w, w3, fmaf(xa3.z, w2,
                        fmaf(xa3.y, w1, fmaf(xa3.x, w0, acc[3][j]))));
        }
        r2[0] = fmaf(xa0.w, xa0.w, fmaf(xa0.z, xa0.z,
                fmaf(xa0.y, xa0.y, fmaf(xa0.x, xa0.x, r2[0]))));
        r2[1] = fmaf(xa1.w, xa1.w, fmaf(xa1.z, xa1.z,
                fmaf(xa1.y, xa1.y, fmaf(xa1.x, xa1.x, r2[1]))));
        r2[2] = fmaf(xa2.w, xa2.w, fmaf(xa2.z, xa2.z,
                fmaf(xa2.y, xa2.y, fmaf(xa2.x, xa2.x, r2[2]))));
        r2[3] = fmaf(xa3.w, xa3.w, fmaf(xa3.z, xa3.z,
                fmaf(xa3.y, xa3.y, fmaf(xa3.x, xa3.x, r2[3]))));

        xa0 = xb0; xa1 = xb1; xa2 = xb2; xa3 = xb3;
        #pragma unroll
        for (int j = 0; j < 6; ++j) wa[j] = wb[j];
    }

    // ---- DPP reduce over ksl -> FINAL H for this wave's 4 tokens ----
    #pragma unroll
    for (int t = 0; t < 4; ++t) {
        #pragma unroll
        for (int j = 0; j < 6; ++j) acc[t][j] = row16_sum(acc[t][j]);
        r2[t] = row16_sum(r2[t]);
    }
    if (ksl == 0) {
        #pragma unroll
        for (int t = 0; t < 4; ++t) {
            #pragma unroll
            for (int j = 0; j < 6; ++j)
                Hpart[t0 + t][6 * ng + j] = acc[t][j];
            if (ng == 0) Hpart[t0 + t][24] = r2[t];
        }
    }
    __syncthreads();

    // ---- scalar phase: lanes 0..15, one token each (R2-proven) ----
    if (tid < NTOK) {
        const int t = tid;
        float Hp[24];
        #pragma unroll
        for (int q = 0; q < 24; ++q) Hp[q] = Hpart[t][q];
        const float r2v = Hpart[t][24];
        const float r_ = 1.0f / (sqrtf(r2v) * 0.03125f + 1e-6f);

        float Hpre[4], Hpost[4], K[16];
        #pragma unroll
        for (int n = 0; n < 4; ++n)
            Hpre[n] = sigmoid_f(fmaf(r_, Hp[n], beta[n]));
        #pragma unroll
        for (int n = 0; n < 4; ++n)
            Hpost[n] = 2.0f * sigmoid_f(fmaf(r_, Hp[4 + n], beta[4 + n]));
        #pragma unroll
        for (int q = 0; q < 16; ++q)
            K[q] = __expf(fmaf(r_, Hp[8 + q], beta[8 + q]));

        float u0=1.f,u1=1.f,u2=1.f,u3=1.f;
        float v0=1.f,v1=1.f,v2=1.f,v3=1.f;
        for (int itr = 0; itr < 10; ++itr) {
            u0 = 1.0f/(K[0]*v0  + K[1]*v1  + K[2]*v2  + K[3]*v3  + 1e-8f);
            u1 = 1.0f/(K[4]*v0  + K[5]*v1  + K[6]*v2  + K[7]*v3  + 1e-8f);
            u2 = 1.0f/(K[8]*v0  + K[9]*v1  + K[10]*v2 + K[11]*v3 + 1e-8f);
            u3 = 1.0f/(K[12]*v0 + K[13]*v1 + K[14]*v2 + K[15]*v3 + 1e-8f);
            v0 = 1.0f/(K[0]*u0  + K[4]*u1  + K[8]*u2  + K[12]*u3 + 1e-8f);
            v1 = 1.0f/(K[1]*u0  + K[5]*u1  + K[9]*u2  + K[13]*u3 + 1e-8f);
            v2 = 1.0f/(K[2]*u0  + K[6]*u1  + K[10]*u2 + K[14]*u3 + 1e-8f);
            v3 = 1.0f/(K[3]*u0  + K[7]*u1  + K[11]*u2 + K[15]*u3 + 1e-8f);
        }
        smalls[t][0] = Hpre[0];  smalls[t][1] = Hpre[1];
        smalls[t][2] = Hpre[2];  smalls[t][3] = Hpre[3];
        smalls[t][4] = Hpost[0]; smalls[t][5] = Hpost[1];
        smalls[t][6] = Hpost[2]; smalls[t][7] = Hpost[3];
        smalls[t][8]  = u0*K[0]*v0;   smalls[t][9]  = u0*K[1]*v1;
        smalls[t][10] = u0*K[2]*v2;   smalls[t][11] = u0*K[3]*v3;
        smalls[t][12] = u1*K[4]*v0;   smalls[t][13] = u1*K[5]*v1;
        smalls[t][14] = u1*K[6]*v2;   smalls[t][15] = u1*K[7]*v3;
        smalls[t][16] = u2*K[8]*v0;   smalls[t][17] = u2*K[9]*v1;
        smalls[t][18] = u2*K[10]*v2;  smalls[t][19] = u2*K[11]*v3;
        smalls[t][20] = u3*K[12]*v0;  smalls[t][21] = u3*K[13]*v1;
        smalls[t][22] = u3*K[14]*v2;  smalls[t][23] = u3*K[15]*v3;
    }
    __syncthreads();

    // ---- phase C: out = Hpost*h_pre + P@h (R2-proven, fp32) ----
    const int gg = wv;   // n = gg, d = 4*lane..+3
    const float* p0 = h + tok0 * 1024 + 4 * lane;
    float4 ca0, ca1, ca2, ca3, cb0, cb1, cb2, cb3;
    {
        ca0 = *(const float4*)(p0);       ca1 = *(const float4*)(p0 + 256);
        ca2 = *(const float4*)(p0 + 512); ca3 = *(const float4*)(p0 + 768);
        const float* q = p0 + 1024;
        cb0 = *(const float4*)(q);        cb1 = *(const float4*)(q + 256);
        cb2 = *(const float4*)(q + 512);  cb3 = *(const float4*)(q + 768);
    }
    for (int it = 0; it < NTOK; ++it) {
        const long tok = tok0 + it;
        const float4 xm0 = ca0, xm1 = ca1, xm2 = ca2, xm3 = ca3;
        ca0 = cb0; ca1 = cb1; ca2 = cb2; ca3 = cb3;
        if (it + 2 < NTOK) {
            const float* p = p0 + (it + 2) * 1024;
            cb0 = *(const float4*)(p);       cb1 = *(const float4*)(p + 256);
            cb2 = *(const float4*)(p + 512); cb3 = *(const float4*)(p + 768);
        }
        const float hp0 = smalls[it][0], hp1 = smalls[it][1];
        const float hp2 = smalls[it][2], hp3 = smalls[it][3];
        const float hpost = smalls[it][4 + gg];
        const float P0 = smalls[it][8 + 4*gg + 0];
        const float P1 = smalls[it][8 + 4*gg + 1];
        const float P2 = smalls[it][8 + 4*gg + 2];
        const float P3 = smalls[it][8 + 4*gg + 3];

        float4 o;
        {
            const float hpre = hp0*xm0.x + hp1*xm1.x + hp2*xm2.x + hp3*xm3.x;
            o.x = fmaf(hpost, hpre, P0*xm0.x + P1*xm1.x + P2*xm2.x + P3*xm3.x);
        }
        {
            const float hpre = hp0*xm0.y + hp1*xm1.y + hp2*xm2.y + hp3*xm3.y;
            o.y = fmaf(hpost, hpre, P0*xm0.y + P1*xm1.y + P2*xm2.y + P3*xm3.y);
        }
        {
            const float hpre = hp0*xm0.z + hp1*xm1.z + hp2*xm2.z + hp3*xm3.z;
            o.z = fmaf(hpost, hpre, P0*xm0.z + P1*xm1.z + P2*xm2.z + P3*xm3.z);
        }
        {
            const float hpre = hp0*xm0.w + hp1*xm1.w + hp2*xm2.w + hp3*xm3.w;
            o.w = fmaf(hpost, hpre, P0*xm0.w + P1*xm1.w + P2*xm2.w + P3*xm3.w);
        }
        *(float4*)(out + tok * 1024 + gg * 256 + 4 * lane) = o;
    }
}

extern "C" void kernel_launch(void* const* d_in, const int* in_sizes, int n_in,
                              void* d_out, int out_size, void* d_ws, size_t ws_size,
                              hipStream_t stream) {
    const float* h     = (const float*)d_in[0];
    const float* nw    = (const float*)d_in[1];
    const float* w     = (const float*)d_in[2];
    const float* alpha = (const float*)d_in[3];
    const float* beta  = (const float*)d_in[4];
    float* out = (float*)d_out;
    unsigned short* wt = (unsigned short*)d_ws;   // 24*1024*2B = 48KB

    prep_kernel<<<24, 256, 0, stream>>>(nw, w, alpha, wt);
    mhc_kernel<<<2048, 256, 0, stream>>>(h, wt, beta, out);
}

// Round 15
// 280.706 us; speedup vs baseline: 1.7096x; 1.7096x over previous
//
#include <hip/hip_runtime.h>
#include <math.h>

// ManifoldHyperConnectionFuse on MI355X — R14: occupancy 4->6 blocks/CU.
// R13 post-mortem: __launch_bounds__(256,8) made the compiler throttle to
// VGPR=32 -> total spill to scratch-in-HBM (WRITE 1.1GB, 480us). Lesson:
// compiler over-throttles under aggressive min-wave bounds.
// R14 = R12 byte-identical except __launch_bounds__(256,6): 6 waves/SIMD
// needs VGPR<=85 (m69 table), current need is 52 -> fits with headroom,
// no spill expected, occupancy ceiling 38% -> 75%.

#define NTOK 16

__device__ __forceinline__ unsigned short f2bf(float f) {
    unsigned int u = __float_as_uint(f);
    return (unsigned short)((u + 0x7FFFu + ((u >> 16) & 1u)) >> 16);
}
__device__ __forceinline__ float bflo(unsigned int u) {
    return __uint_as_float(u << 16);
}
__device__ __forceinline__ float bfhi(unsigned int u) {
    return __uint_as_float(u & 0xffff0000u);
}
__device__ __forceinline__ float sigmoid_f(float z) {
    return 1.0f / (1.0f + __expf(-z));
}

// sum over each aligned 16-lane row via DPP row_ror (VALU-only)
__device__ __forceinline__ float row16_sum(float x) {
    x += __int_as_float(__builtin_amdgcn_update_dpp(
        0, __float_as_int(x), 0x121, 0xf, 0xf, false)); // row_ror:1
    x += __int_as_float(__builtin_amdgcn_update_dpp(
        0, __float_as_int(x), 0x122, 0xf, 0xf, false)); // row_ror:2
    x += __int_as_float(__builtin_amdgcn_update_dpp(
        0, __float_as_int(x), 0x124, 0xf, 0xf, false)); // row_ror:4
    x += __int_as_float(__builtin_amdgcn_update_dpp(
        0, __float_as_int(x), 0x128, 0xf, 0xf, false)); // row_ror:8
    return x;
}

// ---- prep: fold alpha*nw*w -> bf16 wt[24][1024] (n-major) in d_ws ----
__global__ __launch_bounds__(256)
void prep_kernel(const float* __restrict__ nw,
                 const float* __restrict__ w,
                 const float* __restrict__ alpha,
                 unsigned short* __restrict__ wt)
{
    const int tid = blockIdx.x * 256 + threadIdx.x;   // 6144 threads
    const int flat = 4 * tid;                          // w is [k][n], flat=k*24+n
    const float4 w4 = *(const float4*)(w + flat);
    const float a0 = alpha[0], a1 = alpha[1], a2 = alpha[2];
    const float vals[4] = {w4.x, w4.y, w4.z, w4.w};
    #pragma unroll
    for (int c = 0; c < 4; ++c) {
        const int f = flat + c;
        const int k = f / 24;
        const int n = f - 24 * k;
        const float as = (n < 4) ? a0 : ((n < 8) ? a1 : a2);
        wt[n * 1024 + k] = f2bf(as * nw[k] * vals[c]);
    }
}

__global__ __launch_bounds__(256, 6)
void mhc_kernel(const float* __restrict__ h,
                const unsigned short* __restrict__ wt,
                const float* __restrict__ beta,
                float* __restrict__ out)
{
    const int tid  = threadIdx.x;
    const int lane = tid & 63;
    const int wv   = tid >> 6;     // wave id: owns tokens [4wv, 4wv+4)
    const int ksl  = lane & 15;    // k-slice lane
    const int ng   = lane >> 4;    // n-group (6 n's each)

    __shared__ float Hpart[NTOK][28];   // [0:24) H, [24] r2
    __shared__ float smalls[NTOK][26];  // Hpre, Hpost, P

    const long tok0 = (long)blockIdx.x * NTOK;
    const int t0 = 4 * wv;
    const float* ph = h + (tok0 + t0) * 1024 + 4 * ksl;
    const unsigned short* pw = wt + (6 * ng) * 1024 + 4 * ksl;

    // ---- phase A: acc-resident, x & w double-buffered across e ----
    float acc[4][6], r2[4];
    #pragma unroll
    for (int t = 0; t < 4; ++t) {
        r2[t] = 0.f;
        #pragma unroll
        for (int j = 0; j < 6; ++j) acc[t][j] = 0.f;
    }

    float4 xa0, xa1, xa2, xa3;
    uint2  wa[6];
    xa0 = *(const float4*)(ph);
    xa1 = *(const float4*)(ph + 1024);
    xa2 = *(const float4*)(ph + 2048);
    xa3 = *(const float4*)(ph + 3072);
    #pragma unroll
    for (int j = 0; j < 6; ++j)
        wa[j] = *(const uint2*)(pw + j * 1024);

    #pragma unroll 1
    for (int e = 0; e < 16; ++e) {
        float4 xb0, xb1, xb2, xb3;
        uint2  wb[6];
        if (e + 1 < 16) {                 // issue e+1 loads before e compute
            const float* p = ph + (e + 1) * 64;
            xb0 = *(const float4*)(p);
            xb1 = *(const float4*)(p + 1024);
            xb2 = *(const float4*)(p + 2048);
            xb3 = *(const float4*)(p + 3072);
            const unsigned short* q = pw + (e + 1) * 64;
            #pragma unroll
            for (int j = 0; j < 6; ++j)
                wb[j] = *(const uint2*)(q + j * 1024);
        }

        #pragma unroll
        for (int j = 0; j < 6; ++j) {
            const float w0 = bflo(wa[j].x), w1 = bfhi(wa[j].x);
            const float w2 = bflo(wa[j].y), w3 = bfhi(wa[j].y);
            acc[0][j] = fmaf(xa0.w, w3, fmaf(xa0.z, w2,
                        fmaf(xa0.y, w1, fmaf(xa0.x, w0, acc[0][j]))));
            acc[1][j] = fmaf(xa1.w, w3, fmaf(xa1.z, w2,
                        fmaf(xa1.y, w1, fmaf(xa1.x, w0, acc[1][j]))));
            acc[2][j] = fmaf(xa2.w, w3, fmaf(xa2.z, w2,
                        fmaf(xa2.y, w1, fmaf(xa2.x, w0, acc[2][j]))));
            acc[3][j] = fmaf(xa3.w, w3, fmaf(xa3.z, w2,
                        fmaf(xa3.y, w1, fmaf(xa3.x, w0, acc[3][j]))));
        }
        r2[0] = fmaf(xa0.w, xa0.w, fmaf(xa0.z, xa0.z,
                fmaf(xa0.y, xa0.y, fmaf(xa0.x, xa0.x, r2[0]))));
        r2[1] = fmaf(xa1.w, xa1.w, fmaf(xa1.z, xa1.z,
                fmaf(xa1.y, xa1.y, fmaf(xa1.x, xa1.x, r2[1]))));
        r2[2] = fmaf(xa2.w, xa2.w, fmaf(xa2.z, xa2.z,
                fmaf(xa2.y, xa2.y, fmaf(xa2.x, xa2.x, r2[2]))));
        r2[3] = fmaf(xa3.w, xa3.w, fmaf(xa3.z, xa3.z,
                fmaf(xa3.y, xa3.y, fmaf(xa3.x, xa3.x, r2[3]))));

        xa0 = xb0; xa1 = xb1; xa2 = xb2; xa3 = xb3;
        #pragma unroll
        for (int j = 0; j < 6; ++j) wa[j] = wb[j];
    }

    // ---- DPP reduce over ksl -> FINAL H for this wave's 4 tokens ----
    #pragma unroll
    for (int t = 0; t < 4; ++t) {
        #pragma unroll
        for (int j = 0; j < 6; ++j) acc[t][j] = row16_sum(acc[t][j]);
        r2[t] = row16_sum(r2[t]);
    }
    if (ksl == 0) {
        #pragma unroll
        for (int t = 0; t < 4; ++t) {
            #pragma unroll
            for (int j = 0; j < 6; ++j)
                Hpart[t0 + t][6 * ng + j] = acc[t][j];
            if (ng == 0) Hpart[t0 + t][24] = r2[t];
        }
    }
    __syncthreads();

    // ---- scalar phase: lanes 0..15, one token each (R2-proven) ----
    if (tid < NTOK) {
        const int t = tid;
        float Hp[24];
        #pragma unroll
        for (int q = 0; q < 24; ++q) Hp[q] = Hpart[t][q];
        const float r2v = Hpart[t][24];
        const float r_ = 1.0f / (sqrtf(r2v) * 0.03125f + 1e-6f);

        float Hpre[4], Hpost[4], K[16];
        #pragma unroll
        for (int n = 0; n < 4; ++n)
            Hpre[n] = sigmoid_f(fmaf(r_, Hp[n], beta[n]));
        #pragma unroll
        for (int n = 0; n < 4; ++n)
            Hpost[n] = 2.0f * sigmoid_f(fmaf(r_, Hp[4 + n], beta[4 + n]));
        #pragma unroll
        for (int q = 0; q < 16; ++q)
            K[q] = __expf(fmaf(r_, Hp[8 + q], beta[8 + q]));

        float u0=1.f,u1=1.f,u2=1.f,u3=1.f;
        float v0=1.f,v1=1.f,v2=1.f,v3=1.f;
        for (int itr = 0; itr < 10; ++itr) {
            u0 = 1.0f/(K[0]*v0  + K[1]*v1  + K[2]*v2  + K[3]*v3  + 1e-8f);
            u1 = 1.0f/(K[4]*v0  + K[5]*v1  + K[6]*v2  + K[7]*v3  + 1e-8f);
            u2 = 1.0f/(K[8]*v0  + K[9]*v1  + K[10]*v2 + K[11]*v3 + 1e-8f);
            u3 = 1.0f/(K[12]*v0 + K[13]*v1 + K[14]*v2 + K[15]*v3 + 1e-8f);
            v0 = 1.0f/(K[0]*u0  + K[4]*u1  + K[8]*u2  + K[12]*u3 + 1e-8f);
            v1 = 1.0f/(K[1]*u0  + K[5]*u1  + K[9]*u2  + K[13]*u3 + 1e-8f);
            v2 = 1.0f/(K[2]*u0  + K[6]*u1  + K[10]*u2 + K[14]*u3 + 1e-8f);
            v3 = 1.0f/(K[3]*u0  + K[7]*u1  + K[11]*u2 + K[15]*u3 + 1e-8f);
        }
        smalls[t][0] = Hpre[0];  smalls[t][1] = Hpre[1];
        smalls[t][2] = Hpre[2];  smalls[t][3] = Hpre[3];
        smalls[t][4] = Hpost[0]; smalls[t][5] = Hpost[1];
        smalls[t][6] = Hpost[2]; smalls[t][7] = Hpost[3];
        smalls[t][8]  = u0*K[0]*v0;   smalls[t][9]  = u0*K[1]*v1;
        smalls[t][10] = u0*K[2]*v2;   smalls[t][11] = u0*K[3]*v3;
        smalls[t][12] = u1*K[4]*v0;   smalls[t][13] = u1*K[5]*v1;
        smalls[t][14] = u1*K[6]*v2;   smalls[t][15] = u1*K[7]*v3;
        smalls[t][16] = u2*K[8]*v0;   smalls[t][17] = u2*K[9]*v1;
        smalls[t][18] = u2*K[10]*v2;  smalls[t][19] = u2*K[11]*v3;
        smalls[t][20] = u3*K[12]*v0;  smalls[t][21] = u3*K[13]*v1;
        smalls[t][22] = u3*K[14]*v2;  smalls[t][23] = u3*K[15]*v3;
    }
    __syncthreads();

    // ---- phase C: out = Hpost*h_pre + P@h (R2-proven, fp32) ----
    const int gg = wv;   // n = gg, d = 4*lane..+3
    const float* p0 = h + tok0 * 1024 + 4 * lane;
    float4 ca0, ca1, ca2, ca3, cb0, cb1, cb2, cb3;
    {
        ca0 = *(const float4*)(p0);       ca1 = *(const float4*)(p0 + 256);
        ca2 = *(const float4*)(p0 + 512); ca3 = *(const float4*)(p0 + 768);
        const float* q = p0 + 1024;
        cb0 = *(const float4*)(q);        cb1 = *(const float4*)(q + 256);
        cb2 = *(const float4*)(q + 512);  cb3 = *(const float4*)(q + 768);
    }
    for (int it = 0; it < NTOK; ++it) {
        const long tok = tok0 + it;
        const float4 xm0 = ca0, xm1 = ca1, xm2 = ca2, xm3 = ca3;
        ca0 = cb0; ca1 = cb1; ca2 = cb2; ca3 = cb3;
        if (it + 2 < NTOK) {
            const float* p = p0 + (it + 2) * 1024;
            cb0 = *(const float4*)(p);       cb1 = *(const float4*)(p + 256);
            cb2 = *(const float4*)(p + 512); cb3 = *(const float4*)(p + 768);
        }
        const float hp0 = smalls[it][0], hp1 = smalls[it][1];
        const float hp2 = smalls[it][2], hp3 = smalls[it][3];
        const float hpost = smalls[it][4 + gg];
        const float P0 = smalls[it][8 + 4*gg + 0];
        const float P1 = smalls[it][8 + 4*gg + 1];
        const float P2 = smalls[it][8 + 4*gg + 2];
        const float P3 = smalls[it][8 + 4*gg + 3];

        float4 o;
        {
            const float hpre = hp0*xm0.x + hp1*xm1.x + hp2*xm2.x + hp3*xm3.x;
            o.x = fmaf(hpost, hpre, P0*xm0.x + P1*xm1.x + P2*xm2.x + P3*xm3.x);
        }
        {
            const float hpre = hp0*xm0.y + hp1*xm1.y + hp2*xm2.y + hp3*xm3.y;
            o.y = fmaf(hpost, hpre, P0*xm0.y + P1*xm1.y + P2*xm2.y + P3*xm3.y);
        }
        {
            const float hpre = hp0*xm0.z + hp1*xm1.z + hp2*xm2.z + hp3*xm3.z;
            o.z = fmaf(hpost, hpre, P0*xm0.z + P1*xm1.z + P2*xm2.z + P3*xm3.z);
        }
        {
            const float hpre = hp0*xm0.w + hp1*xm1.w + hp2*xm2.w + hp3*xm3.w;
            o.w = fmaf(hpost, hpre, P0*xm0.w + P1*xm1.w + P2*xm2.w + P3*xm3.w);
        }
        *(float4*)(out + tok * 1024 + gg * 256 + 4 * lane) = o;
    }
}

extern "C" void kernel_launch(void* const* d_in, const int* in_sizes, int n_in,
                              void* d_out, int out_size, void* d_ws, size_t ws_size,
                              hipStream_t stream) {
    const float* h     = (const float*)d_in[0];
    const float* nw    = (const float*)d_in[1];
    const float* w     = (const float*)d_in[2];
    const float* alpha = (const float*)d_in[3];
    const float* beta  = (const float*)d_in[4];
    float* out = (float*)d_out;
    unsigned short* wt = (unsigned short*)d_ws;   // 24*1024*2B = 48KB

    prep_kernel<<<24, 256, 0, stream>>>(nw, w, alpha, wt);
    mhc_kernel<<<2048, 256, 0, stream>>>(h, wt, beta, out);
}

// Round 16
// 97.462 us; speedup vs baseline: 4.9239x; 2.8802x over previous
//
#include <hip/hip_runtime.h>
#include <math.h>

// ManifoldHyperConnectionFuse on MI355X — R15: 8 tokens/wave (ILP, not TLP).
// R13/R14 proved the occupancy lever dead: ANY min-wave hint makes the
// compiler slash VGPR below need and spill to HBM. Revert to R12's proven
// (256,4) config and instead DOUBLE per-wave ILP: each wave owns 8 tokens
// (8 independent FMA chains per weight load, 8 x-loads in flight per
// e-iteration). Accumulators are loop-carried -> allocator must keep them
// (R10/R12-proven). NTOK=32/block, grid=1024. Everything downstream
// identical to R12 (scalar phase lanes 0..31, phase C 32 iterations).

#define NTOK 32

__device__ __forceinline__ unsigned short f2bf(float f) {
    unsigned int u = __float_as_uint(f);
    return (unsigned short)((u + 0x7FFFu + ((u >> 16) & 1u)) >> 16);
}
__device__ __forceinline__ float bflo(unsigned int u) {
    return __uint_as_float(u << 16);
}
__device__ __forceinline__ float bfhi(unsigned int u) {
    return __uint_as_float(u & 0xffff0000u);
}
__device__ __forceinline__ float sigmoid_f(float z) {
    return 1.0f / (1.0f + __expf(-z));
}

// sum over each aligned 16-lane row via DPP row_ror (VALU-only)
__device__ __forceinline__ float row16_sum(float x) {
    x += __int_as_float(__builtin_amdgcn_update_dpp(
        0, __float_as_int(x), 0x121, 0xf, 0xf, false)); // row_ror:1
    x += __int_as_float(__builtin_amdgcn_update_dpp(
        0, __float_as_int(x), 0x122, 0xf, 0xf, false)); // row_ror:2
    x += __int_as_float(__builtin_amdgcn_update_dpp(
        0, __float_as_int(x), 0x124, 0xf, 0xf, false)); // row_ror:4
    x += __int_as_float(__builtin_amdgcn_update_dpp(
        0, __float_as_int(x), 0x128, 0xf, 0xf, false)); // row_ror:8
    return x;
}

// ---- prep: fold alpha*nw*w -> bf16 wt[24][1024] (n-major) in d_ws ----
__global__ __launch_bounds__(256)
void prep_kernel(const float* __restrict__ nw,
                 const float* __restrict__ w,
                 const float* __restrict__ alpha,
                 unsigned short* __restrict__ wt)
{
    const int tid = blockIdx.x * 256 + threadIdx.x;   // 6144 threads
    const int flat = 4 * tid;                          // w is [k][n], flat=k*24+n
    const float4 w4 = *(const float4*)(w + flat);
    const float a0 = alpha[0], a1 = alpha[1], a2 = alpha[2];
    const float vals[4] = {w4.x, w4.y, w4.z, w4.w};
    #pragma unroll
    for (int c = 0; c < 4; ++c) {
        const int f = flat + c;
        const int k = f / 24;
        const int n = f - 24 * k;
        const float as = (n < 4) ? a0 : ((n < 8) ? a1 : a2);
        wt[n * 1024 + k] = f2bf(as * nw[k] * vals[c]);
    }
}

__global__ __launch_bounds__(256, 4)
void mhc_kernel(const float* __restrict__ h,
                const unsigned short* __restrict__ wt,
                const float* __restrict__ beta,
                float* __restrict__ out)
{
    const int tid  = threadIdx.x;
    const int lane = tid & 63;
    const int wv   = tid >> 6;     // wave id: owns tokens [8wv, 8wv+8)
    const int ksl  = lane & 15;    // k-slice lane
    const int ng   = lane >> 4;    // n-group (6 n's each)

    __shared__ float Hpart[NTOK][28];   // [0:24) H, [24] r2
    __shared__ float smalls[NTOK][26];  // Hpre, Hpost, P

    const long tok0 = (long)blockIdx.x * NTOK;
    const int t0 = 8 * wv;
    const float* ph = h + (tok0 + t0) * 1024 + 4 * ksl;
    const unsigned short* pw = wt + (6 * ng) * 1024 + 4 * ksl;

    // ---- phase A: 8 token-chains per wave, w double-buffered ----
    float acc[8][6], r2[8];
    #pragma unroll
    for (int t = 0; t < 8; ++t) {
        r2[t] = 0.f;
        #pragma unroll
        for (int j = 0; j < 6; ++j) acc[t][j] = 0.f;
    }

    uint2 wa[6];
    #pragma unroll
    for (int j = 0; j < 6; ++j)
        wa[j] = *(const uint2*)(pw + j * 1024);

    #pragma unroll 1
    for (int e = 0; e < 16; ++e) {
        // issue this iteration's 8 x-loads (8 independent chains in flight)
        float4 x4[8];
        #pragma unroll
        for (int t = 0; t < 8; ++t)
            x4[t] = *(const float4*)(ph + t * 1024 + 64 * e);

        // prefetch next w (L2-hot)
        uint2 wb[6];
        if (e + 1 < 16) {
            const unsigned short* q = pw + (e + 1) * 64;
            #pragma unroll
            for (int j = 0; j < 6; ++j)
                wb[j] = *(const uint2*)(q + j * 1024);
        }

        #pragma unroll
        for (int j = 0; j < 6; ++j) {
            const float w0 = bflo(wa[j].x), w1 = bfhi(wa[j].x);
            const float w2 = bflo(wa[j].y), w3 = bfhi(wa[j].y);
            #pragma unroll
            for (int t = 0; t < 8; ++t) {
                acc[t][j] = fmaf(x4[t].w, w3, fmaf(x4[t].z, w2,
                            fmaf(x4[t].y, w1, fmaf(x4[t].x, w0, acc[t][j]))));
            }
        }
        #pragma unroll
        for (int t = 0; t < 8; ++t) {
            r2[t] = fmaf(x4[t].w, x4[t].w, fmaf(x4[t].z, x4[t].z,
                    fmaf(x4[t].y, x4[t].y, fmaf(x4[t].x, x4[t].x, r2[t]))));
        }

        #pragma unroll
        for (int j = 0; j < 6; ++j) wa[j] = wb[j];
    }

    // ---- DPP reduce over ksl -> FINAL H for this wave's 8 tokens ----
    #pragma unroll
    for (int t = 0; t < 8; ++t) {
        #pragma unroll
        for (int j = 0; j < 6; ++j) acc[t][j] = row16_sum(acc[t][j]);
        r2[t] = row16_sum(r2[t]);
    }
    if (ksl == 0) {
        #pragma unroll
        for (int t = 0; t < 8; ++t) {
            #pragma unroll
            for (int j = 0; j < 6; ++j)
                Hpart[t0 + t][6 * ng + j] = acc[t][j];
            if (ng == 0) Hpart[t0 + t][24] = r2[t];
        }
    }
    __syncthreads();

    // ---- scalar phase: lanes 0..31 of wave 0, one token each ----
    if (tid < NTOK) {
        const int t = tid;
        float Hp[24];
        #pragma unroll
        for (int q = 0; q < 24; ++q) Hp[q] = Hpart[t][q];
        const float r2v = Hpart[t][24];
        const float r_ = 1.0f / (sqrtf(r2v) * 0.03125f + 1e-6f);

        float Hpre[4], Hpost[4], K[16];
        #pragma unroll
        for (int n = 0; n < 4; ++n)
            Hpre[n] = sigmoid_f(fmaf(r_, Hp[n], beta[n]));
        #pragma unroll
        for (int n = 0; n < 4; ++n)
            Hpost[n] = 2.0f * sigmoid_f(fmaf(r_, Hp[4 + n], beta[4 + n]));
        #pragma unroll
        for (int q = 0; q < 16; ++q)
            K[q] = __expf(fmaf(r_, Hp[8 + q], beta[8 + q]));

        float u0=1.f,u1=1.f,u2=1.f,u3=1.f;
        float v0=1.f,v1=1.f,v2=1.f,v3=1.f;
        for (int itr = 0; itr < 10; ++itr) {
            u0 = 1.0f/(K[0]*v0  + K[1]*v1  + K[2]*v2  + K[3]*v3  + 1e-8f);
            u1 = 1.0f/(K[4]*v0  + K[5]*v1  + K[6]*v2  + K[7]*v3  + 1e-8f);
            u2 = 1.0f/(K[8]*v0  + K[9]*v1  + K[10]*v2 + K[11]*v3 + 1e-8f);
            u3 = 1.0f/(K[12]*v0 + K[13]*v1 + K[14]*v2 + K[15]*v3 + 1e-8f);
            v0 = 1.0f/(K[0]*u0  + K[4]*u1  + K[8]*u2  + K[12]*u3 + 1e-8f);
            v1 = 1.0f/(K[1]*u0  + K[5]*u1  + K[9]*u2  + K[13]*u3 + 1e-8f);
            v2 = 1.0f/(K[2]*u0  + K[6]*u1  + K[10]*u2 + K[14]*u3 + 1e-8f);
            v3 = 1.0f/(K[3]*u0  + K[7]*u1  + K[11]*u2 + K[15]*u3 + 1e-8f);
        }
        smalls[t][0] = Hpre[0];  smalls[t][1] = Hpre[1];
        smalls[t][2] = Hpre[2];  smalls[t][3] = Hpre[3];
        smalls[t][4] = Hpost[0]; smalls[t][5] = Hpost[1];
        smalls[t][6] = Hpost[2]; smalls[t][7] = Hpost[3];
        smalls[t][8]  = u0*K[0]*v0;   smalls[t][9]  = u0*K[1]*v1;
        smalls[t][10] = u0*K[2]*v2;   smalls[t][11] = u0*K[3]*v3;
        smalls[t][12] = u1*K[4]*v0;   smalls[t][13] = u1*K[5]*v1;
        smalls[t][14] = u1*K[6]*v2;   smalls[t][15] = u1*K[7]*v3;
        smalls[t][16] = u2*K[8]*v0;   smalls[t][17] = u2*K[9]*v1;
        smalls[t][18] = u2*K[10]*v2;  smalls[t][19] = u2*K[11]*v3;
        smalls[t][20] = u3*K[12]*v0;  smalls[t][21] = u3*K[13]*v1;
        smalls[t][22] = u3*K[14]*v2;  smalls[t][23] = u3*K[15]*v3;
    }
    __syncthreads();

    // ---- phase C: out = Hpost*h_pre + P@h (R2-proven, fp32) ----
    const int gg = wv;   // n = gg, d = 4*lane..+3
    const float* p0 = h + tok0 * 1024 + 4 * lane;
    float4 ca0, ca1, ca2, ca3, cb0, cb1, cb2, cb3;
    {
        ca0 = *(const float4*)(p0);       ca1 = *(const float4*)(p0 + 256);
        ca2 = *(const float4*)(p0 + 512); ca3 = *(const float4*)(p0 + 768);
        const float* q = p0 + 1024;
        cb0 = *(const float4*)(q);        cb1 = *(const float4*)(q + 256);
        cb2 = *(const float4*)(q + 512);  cb3 = *(const float4*)(q + 768);
    }
    for (int it = 0; it < NTOK; ++it) {
        const long tok = tok0 + it;
        const float4 xm0 = ca0, xm1 = ca1, xm2 = ca2, xm3 = ca3;
        ca0 = cb0; ca1 = cb1; ca2 = cb2; ca3 = cb3;
        if (it + 2 < NTOK) {
            const float* p = p0 + (it + 2) * 1024;
            cb0 = *(const float4*)(p);       cb1 = *(const float4*)(p + 256);
            cb2 = *(const float4*)(p + 512); cb3 = *(const float4*)(p + 768);
        }
        const float hp0 = smalls[it][0], hp1 = smalls[it][1];
        const float hp2 = smalls[it][2], hp3 = smalls[it][3];
        const float hpost = smalls[it][4 + gg];
        const float P0 = smalls[it][8 + 4*gg + 0];
        const float P1 = smalls[it][8 + 4*gg + 1];
        const float P2 = smalls[it][8 + 4*gg + 2];
        const float P3 = smalls[it][8 + 4*gg + 3];

        float4 o;
        {
            const float hpre = hp0*xm0.x + hp1*xm1.x + hp2*xm2.x + hp3*xm3.x;
            o.x = fmaf(hpost, hpre, P0*xm0.x + P1*xm1.x + P2*xm2.x + P3*xm3.x);
        }
        {
            const float hpre = hp0*xm0.y + hp1*xm1.y + hp2*xm2.y + hp3*xm3.y;
            o.y = fmaf(hpost, hpre, P0*xm0.y + P1*xm1.y + P2*xm2.y + P3*xm3.y);
        }
        {
            const float hpre = hp0*xm0.z + hp1*xm1.z + hp2*xm2.z + hp3*xm3.z;
            o.z = fmaf(hpost, hpre, P0*xm0.z + P1*xm1.z + P2*xm2.z + P3*xm3.z);
        }
        {
            const float hpre = hp0*xm0.w + hp1*xm1.w + hp2*xm2.w + hp3*xm3.w;
            o.w = fmaf(hpost, hpre, P0*xm0.w + P1*xm1.w + P2*xm2.w + P3*xm3.w);
        }
        *(float4*)(out + tok * 1024 + gg * 256 + 4 * lane) = o;
    }
}

extern "C" void kernel_launch(void* const* d_in, const int* in_sizes, int n_in,
                              void* d_out, int out_size, void* d_ws, size_t ws_size,
                              hipStream_t stream) {
    const float* h     = (const float*)d_in[0];
    const float* nw    = (const float*)d_in[1];
    const float* w     = (const float*)d_in[2];
    const float* alpha = (const float*)d_in[3];
    const float* beta  = (const float*)d_in[4];
    float* out = (float*)d_out;
    unsigned short* wt = (unsigned short*)d_ws;   // 24*1024*2B = 48KB

    prep_kernel<<<24, 256, 0, stream>>>(nw, w, alpha, wt);
    mhc_kernel<<<1024, 256, 0, stream>>>(h, wt, beta, out);
}

// Round 17
// 89.027 us; speedup vs baseline: 5.3904x; 1.0947x over previous
//
#include <hip/hip_runtime.h>
#include <math.h>

// ManifoldHyperConnectionFuse on MI355X — R16: bulk LDS stage + tile reuse.
// R13-R15 law (5 data points): the compiler caps VGPR at occupancy-boundary
// values (52/64/84) regardless of bounds and SPILLS anything bigger ->
// neither TLP nor per-wave ILP can grow. R16 moves the latency problem to
// LDS instead: one bulk 32KB global->LDS stage per block (8 outstanding
// 16B loads/thread -> MLP from bulk issue, not loop residency), phase A
// reads x from LDS (cheap, broadcast), phase C RE-READS the tile from LDS
// (deletes the whole second global read of h). Wave owns 2 tokens ->
// ~65 live regs, under the compiler's comfort point.
// NTOK=8, grid=4096, 4 blocks/CU (142KB LDS), w table in d_ws (R12-proven).

#define NTOK 8

__device__ __forceinline__ unsigned short f2bf(float f) {
    unsigned int u = __float_as_uint(f);
    return (unsigned short)((u + 0x7FFFu + ((u >> 16) & 1u)) >> 16);
}
__device__ __forceinline__ float bflo(unsigned int u) {
    return __uint_as_float(u << 16);
}
__device__ __forceinline__ float bfhi(unsigned int u) {
    return __uint_as_float(u & 0xffff0000u);
}
__device__ __forceinline__ float sigmoid_f(float z) {
    return 1.0f / (1.0f + __expf(-z));
}

// sum over each aligned 16-lane row via DPP row_ror (VALU-only)
__device__ __forceinline__ float row16_sum(float x) {
    x += __int_as_float(__builtin_amdgcn_update_dpp(
        0, __float_as_int(x), 0x121, 0xf, 0xf, false)); // row_ror:1
    x += __int_as_float(__builtin_amdgcn_update_dpp(
        0, __float_as_int(x), 0x122, 0xf, 0xf, false)); // row_ror:2
    x += __int_as_float(__builtin_amdgcn_update_dpp(
        0, __float_as_int(x), 0x124, 0xf, 0xf, false)); // row_ror:4
    x += __int_as_float(__builtin_amdgcn_update_dpp(
        0, __float_as_int(x), 0x128, 0xf, 0xf, false)); // row_ror:8
    return x;
}

// ---- prep: fold alpha*nw*w -> bf16 wt[24][1024] (n-major) in d_ws ----
__global__ __launch_bounds__(256)
void prep_kernel(const float* __restrict__ nw,
                 const float* __restrict__ w,
                 const float* __restrict__ alpha,
                 unsigned short* __restrict__ wt)
{
    const int tid = blockIdx.x * 256 + threadIdx.x;   // 6144 threads
    const int flat = 4 * tid;                          // w is [k][n], flat=k*24+n
    const float4 w4 = *(const float4*)(w + flat);
    const float a0 = alpha[0], a1 = alpha[1], a2 = alpha[2];
    const float vals[4] = {w4.x, w4.y, w4.z, w4.w};
    #pragma unroll
    for (int c = 0; c < 4; ++c) {
        const int f = flat + c;
        const int k = f / 24;
        const int n = f - 24 * k;
        const float as = (n < 4) ? a0 : ((n < 8) ? a1 : a2);
        wt[n * 1024 + k] = f2bf(as * nw[k] * vals[c]);
    }
}

__global__ __launch_bounds__(256, 4)
void mhc_kernel(const float* __restrict__ h,
                const unsigned short* __restrict__ wt,
                const float* __restrict__ beta,
                float* __restrict__ out)
{
    const int tid  = threadIdx.x;
    const int lane = tid & 63;
    const int wv   = tid >> 6;     // wave id: owns tokens {2wv, 2wv+1}
    const int ksl  = lane & 15;    // k-slice lane
    const int ng   = lane >> 4;    // n-group (6 n's each)

    __shared__ float tile[NTOK * 1024];   // 32 KB h-tile
    __shared__ float Hpart[NTOK][28];     // [0:24) H, [24] r2
    __shared__ float smalls[NTOK][26];    // Hpre, Hpost, P

    const long tok0 = (long)blockIdx.x * NTOK;

    // ---- bulk stage: 8 x (256thr x 16B) = 32KB, all loads issued at once ----
    {
        const float* src = h + tok0 * 1024 + 4 * tid;
        float4 st[8];
        #pragma unroll
        for (int i = 0; i < 8; ++i)
            st[i] = *(const float4*)(src + 1024 * i);
        #pragma unroll
        for (int i = 0; i < 8; ++i)
            *(float4*)(tile + 1024 * i + 4 * tid) = st[i];
    }
    __syncthreads();

    // ---- phase A: x from LDS, w from d_ws (L2), wave owns 2 tokens ----
    const float* xt0 = tile + (2 * wv) * 1024 + 4 * ksl;
    const float* xt1 = xt0 + 1024;
    const unsigned short* pw = wt + (6 * ng) * 1024 + 4 * ksl;

    float acc0[6], acc1[6];
    float r20 = 0.f, r21 = 0.f;
    #pragma unroll
    for (int j = 0; j < 6; ++j) { acc0[j] = 0.f; acc1[j] = 0.f; }

    uint2 wa[6];
    #pragma unroll
    for (int j = 0; j < 6; ++j) wa[j] = *(const uint2*)(pw + j * 1024);

    #pragma unroll 1
    for (int e = 0; e < 16; ++e) {
        const float4 xa = *(const float4*)(xt0 + 64 * e);   // LDS, broadcast
        const float4 xb = *(const float4*)(xt1 + 64 * e);
        uint2 wb[6];
        if (e + 1 < 16) {                 // next w chunk (L2-hot)
            const unsigned short* q = pw + (e + 1) * 64;
            #pragma unroll
            for (int j = 0; j < 6; ++j) wb[j] = *(const uint2*)(q + j * 1024);
        }

        #pragma unroll
        for (int j = 0; j < 6; ++j) {
            const float w0 = bflo(wa[j].x), w1 = bfhi(wa[j].x);
            const float w2 = bflo(wa[j].y), w3 = bfhi(wa[j].y);
            acc0[j] = fmaf(xa.w, w3, fmaf(xa.z, w2,
                      fmaf(xa.y, w1, fmaf(xa.x, w0, acc0[j]))));
            acc1[j] = fmaf(xb.w, w3, fmaf(xb.z, w2,
                      fmaf(xb.y, w1, fmaf(xb.x, w0, acc1[j]))));
        }
        r20 = fmaf(xa.w, xa.w, fmaf(xa.z, xa.z,
              fmaf(xa.y, xa.y, fmaf(xa.x, xa.x, r20))));
        r21 = fmaf(xb.w, xb.w, fmaf(xb.z, xb.z,
              fmaf(xb.y, xb.y, fmaf(xb.x, xb.x, r21))));

        #pragma unroll
        for (int j = 0; j < 6; ++j) wa[j] = wb[j];
    }

    // ---- DPP reduce over ksl -> FINAL H for this wave's 2 tokens ----
    #pragma unroll
    for (int j = 0; j < 6; ++j) {
        acc0[j] = row16_sum(acc0[j]);
        acc1[j] = row16_sum(acc1[j]);
    }
    r20 = row16_sum(r20);
    r21 = row16_sum(r21);

    if (ksl == 0) {
        const int t0 = 2 * wv;
        #pragma unroll
        for (int j = 0; j < 6; ++j) {
            Hpart[t0][6 * ng + j]     = acc0[j];
            Hpart[t0 + 1][6 * ng + j] = acc1[j];
        }
        if (ng == 0) { Hpart[t0][24] = r20; Hpart[t0 + 1][24] = r21; }
    }
    __syncthreads();

    // ---- scalar phase: lanes 0..7, one token each (R2-proven) ----
    if (tid < NTOK) {
        const int t = tid;
        float Hp[24];
        #pragma unroll
        for (int q = 0; q < 24; ++q) Hp[q] = Hpart[t][q];
        const float r2v = Hpart[t][24];
        const float r_ = 1.0f / (sqrtf(r2v) * 0.03125f + 1e-6f);

        float Hpre[4], Hpost[4], K[16];
        #pragma unroll
        for (int n = 0; n < 4; ++n)
            Hpre[n] = sigmoid_f(fmaf(r_, Hp[n], beta[n]));
        #pragma unroll
        for (int n = 0; n < 4; ++n)
            Hpost[n] = 2.0f * sigmoid_f(fmaf(r_, Hp[4 + n], beta[4 + n]));
        #pragma unroll
        for (int q = 0; q < 16; ++q)
            K[q] = __expf(fmaf(r_, Hp[8 + q], beta[8 + q]));

        float u0=1.f,u1=1.f,u2=1.f,u3=1.f;
        float v0=1.f,v1=1.f,v2=1.f,v3=1.f;
        for (int itr = 0; itr < 10; ++itr) {
            u0 = 1.0f/(K[0]*v0  + K[1]*v1  + K[2]*v2  + K[3]*v3  + 1e-8f);
            u1 = 1.0f/(K[4]*v0  + K[5]*v1  + K[6]*v2  + K[7]*v3  + 1e-8f);
            u2 = 1.0f/(K[8]*v0  + K[9]*v1  + K[10]*v2 + K[11]*v3 + 1e-8f);
            u3 = 1.0f/(K[12]*v0 + K[13]*v1 + K[14]*v2 + K[15]*v3 + 1e-8f);
            v0 = 1.0f/(K[0]*u0  + K[4]*u1  + K[8]*u2  + K[12]*u3 + 1e-8f);
            v1 = 1.0f/(K[1]*u0  + K[5]*u1  + K[9]*u2  + K[13]*u3 + 1e-8f);
            v2 = 1.0f/(K[2]*u0  + K[6]*u1  + K[10]*u2 + K[14]*u3 + 1e-8f);
            v3 = 1.0f/(K[3]*u0  + K[7]*u1  + K[11]*u2 + K[15]*u3 + 1e-8f);
        }
        smalls[t][0] = Hpre[0];  smalls[t][1] = Hpre[1];
        smalls[t][2] = Hpre[2];  smalls[t][3] = Hpre[3];
        smalls[t][4] = Hpost[0]; smalls[t][5] = Hpost[1];
        smalls[t][6] = Hpost[2]; smalls[t][7] = Hpost[3];
        smalls[t][8]  = u0*K[0]*v0;   smalls[t][9]  = u0*K[1]*v1;
        smalls[t][10] = u0*K[2]*v2;   smalls[t][11] = u0*K[3]*v3;
        smalls[t][12] = u1*K[4]*v0;   smalls[t][13] = u1*K[5]*v1;
        smalls[t][14] = u1*K[6]*v2;   smalls[t][15] = u1*K[7]*v3;
        smalls[t][16] = u2*K[8]*v0;   smalls[t][17] = u2*K[9]*v1;
        smalls[t][18] = u2*K[10]*v2;  smalls[t][19] = u2*K[11]*v3;
        smalls[t][20] = u3*K[12]*v0;  smalls[t][21] = u3*K[13]*v1;
        smalls[t][22] = u3*K[14]*v2;  smalls[t][23] = u3*K[15]*v3;
    }
    __syncthreads();

    // ---- phase C: x from the LDS tile (no global h re-read) ----
    const int gg = wv;   // n = gg, d = 4*lane..+3
    for (int it = 0; it < NTOK; ++it) {
        const float* tl = tile + it * 1024 + 4 * lane;
        const float4 xm0 = *(const float4*)(tl);
        const float4 xm1 = *(const float4*)(tl + 256);
        const float4 xm2 = *(const float4*)(tl + 512);
        const float4 xm3 = *(const float4*)(tl + 768);

        const float hp0 = smalls[it][0], hp1 = smalls[it][1];
        const float hp2 = smalls[it][2], hp3 = smalls[it][3];
        const float hpost = smalls[it][4 + gg];
        const float P0 = smalls[it][8 + 4*gg + 0];
        const float P1 = smalls[it][8 + 4*gg + 1];
        const float P2 = smalls[it][8 + 4*gg + 2];
        const float P3 = smalls[it][8 + 4*gg + 3];

        float4 o;
        {
            const float hpre = hp0*xm0.x + hp1*xm1.x + hp2*xm2.x + hp3*xm3.x;
            o.x = fmaf(hpost, hpre, P0*xm0.x + P1*xm1.x + P2*xm2.x + P3*xm3.x);
        }
        {
            const float hpre = hp0*xm0.y + hp1*xm1.y + hp2*xm2.y + hp3*xm3.y;
            o.y = fmaf(hpost, hpre, P0*xm0.y + P1*xm1.y + P2*xm2.y + P3*xm3.y);
        }
        {
            const float hpre = hp0*xm0.z + hp1*xm1.z + hp2*xm2.z + hp3*xm3.z;
            o.z = fmaf(hpost, hpre, P0*xm0.z + P1*xm1.z + P2*xm2.z + P3*xm3.z);
        }
        {
            const float hpre = hp0*xm0.w + hp1*xm1.w + hp2*xm2.w + hp3*xm3.w;
            o.w = fmaf(hpost, hpre, P0*xm0.w + P1*xm1.w + P2*xm2.w + P3*xm3.w);
        }
        *(float4*)(out + (tok0 + it) * 1024 + gg * 256 + 4 * lane) = o;
    }
}

extern "C" void kernel_launch(void* const* d_in, const int* in_sizes, int n_in,
                              void* d_out, int out_size, void* d_ws, size_t ws_size,
                              hipStream_t stream) {
    const float* h     = (const float*)d_in[0];
    const float* nw    = (const float*)d_in[1];
    const float* w     = (const float*)d_in[2];
    const float* alpha = (const float*)d_in[3];
    const float* beta  = (const float*)d_in[4];
    float* out = (float*)d_out;
    unsigned short* wt = (unsigned short*)d_ws;   // 24*1024*2B = 48KB

    prep_kernel<<<24, 256, 0, stream>>>(nw, w, alpha, wt);
    // 32768 tokens / 8 per block = 4096 blocks
    mhc_kernel<<<4096, 256, 0, stream>>>(h, wt, beta, out);
}